// Round 3
// baseline (163.547 us; speedup 1.0000x reference)
//
#include <hip/hip_runtime.h>
#include <hip/hip_bf16.h>

typedef __bf16 bf16x8 __attribute__((ext_vector_type(8)));
typedef __bf16 bf16x4 __attribute__((ext_vector_type(4)));
typedef float  f32x4  __attribute__((ext_vector_type(4)));
typedef unsigned int u32x4 __attribute__((ext_vector_type(4)));

// ---------------------------------------------------------------------------
// Transpose + cast fp32 -> bf16:  dst[c][r] = (bf16)src[r][c]
// grid: (C/32, R/32), block 256 (32x8)
// ---------------------------------------------------------------------------
__global__ void tcast(const float* __restrict__ src, __bf16* __restrict__ dst,
                      int R, int C) {
    __shared__ float tile[32][33];
    const int bc = blockIdx.x * 32;   // col base in src
    const int br = blockIdx.y * 32;   // row base in src
    const int tx = threadIdx.x & 31;
    const int ty = threadIdx.x >> 5;  // 0..7
#pragma unroll
    for (int p = 0; p < 4; ++p)
        tile[ty + p * 8][tx] = src[(size_t)(br + ty + p * 8) * C + bc + tx];
    __syncthreads();
#pragma unroll
    for (int p = 0; p < 4; ++p)
        dst[(size_t)(bc + ty + p * 8) * R + br + tx] = (__bf16)tile[tx][ty + p * 8];
}

// ---------------------------------------------------------------------------
// Fused: out[8192][4096](f32) = (inp[8192][4096](f32) @ A) @ B
// A given as At[128][4096] bf16, B given as Bt[4096][128] bf16.
// 256 blocks (1/CU) x 512 threads (8 waves). BM=32 rows per block.
//
// Phase A (BARRIER-FREE): per-wave U[16..32][wn slice] accumulated in regs.
//   MFMA operand fragments are read DIRECTLY from global:
//   - A-frag: inp fp32, 16 rows x 32 cols per frag = 16 full 64B lines,
//     converted fp32->bf16 in regs.
//   - B-frag: At bf16 (L2-resident 1 MB), 16 rows x 16B = full lines.
//   No LDS staging, no barriers: latency hidden by unroll-4 ILP + 8 waves.
// One barrier: U (reg, C/D layout) -> sU LDS (bf16, swizzled).
// Phase B: each wave owns all 32 rows x a 512-col slice of out; Bt fragments
//   read directly from global (L2-resident); barrier-free; fp32 stores.
// ---------------------------------------------------------------------------
__global__ __launch_bounds__(512, 1) void fused_lora(
        const float* __restrict__ inp,
        const __bf16* __restrict__ At,
        const __bf16* __restrict__ Bt,
        float* __restrict__ out) {
    __shared__ __align__(16) __bf16 sU[32][128];      // 8 KB
    const int t    = threadIdx.x;
    const int brow = blockIdx.x * 32;
    const int lane = t & 63;
    const int wid  = t >> 6;

    // fragment geometry (shared by both phases)
    const int fr  = lane & 15;
    const int fk8 = (lane >> 4) << 3;   // 0,8,16,24 (k element offset)

    // ---------------- Phase A ----------------
    const int wm = (wid >> 2) << 4;     // 0 / 16
    const int wn = (wid & 3) << 5;      // 0 / 32 / 64 / 96

    f32x4 acc[2] = {};
    const float*  arow = inp + (size_t)(brow + wm + fr) * 4096 + fk8;
    const __bf16* b0   = At  + (size_t)(wn + fr)       * 4096 + fk8;
    const __bf16* b1   = At  + (size_t)(wn + 16 + fr)  * 4096 + fk8;

#pragma unroll 4
    for (int k = 0; k < 4096; k += 32) {
        f32x4 a0 = *reinterpret_cast<const f32x4*>(arow + k);
        f32x4 a1 = *reinterpret_cast<const f32x4*>(arow + k + 4);
        bf16x8 af;
        af[0] = (__bf16)a0[0]; af[1] = (__bf16)a0[1];
        af[2] = (__bf16)a0[2]; af[3] = (__bf16)a0[3];
        af[4] = (__bf16)a1[0]; af[5] = (__bf16)a1[1];
        af[6] = (__bf16)a1[2]; af[7] = (__bf16)a1[3];
        bf16x8 bf0 = *reinterpret_cast<const bf16x8*>(b0 + k);
        bf16x8 bf1 = *reinterpret_cast<const bf16x8*>(b1 + k);
        acc[0] = __builtin_amdgcn_mfma_f32_16x16x32_bf16(af, bf0, acc[0], 0, 0, 0);
        acc[1] = __builtin_amdgcn_mfma_f32_16x16x32_bf16(af, bf1, acc[1], 0, 0, 0);
    }

    // U -> LDS (bf16, swizzled).  C/D layout: col=lane&15, row=(lane>>4)*4+v
    {
        const int r0 = wm + ((lane >> 4) << 2);
#pragma unroll
        for (int n = 0; n < 2; ++n) {
            const int c = wn + n * 16 + fr;
#pragma unroll
            for (int v = 0; v < 4; ++v) {
                const int r = r0 + v;
                sU[r][c ^ ((r & 7) << 3)] = (__bf16)acc[n][v];
            }
        }
    }
    __syncthreads();

    // ---------------- Phase B ----------------
    // Each wave: all 32 rows x 512 cols starting at wid*512. No barriers.
    const int wn2 = wid << 9;

    // hoist U fragments: uf[mf][ks] covers rows mf*16+fr, k = ks*32+fk8..+8
    bf16x8 uf[2][4];
#pragma unroll
    for (int mf = 0; mf < 2; ++mf) {
        const int r = mf * 16 + fr;
#pragma unroll
        for (int ks = 0; ks < 4; ++ks)
            uf[mf][ks] = *reinterpret_cast<const bf16x8*>(
                &sU[r][(ks * 32 + fk8) ^ ((r & 7) << 3)]);
    }

#pragma unroll 1
    for (int nc = 0; nc < 8; ++nc) {
        const int ncol = wn2 + nc * 64;
        // per-lane base into Bt for this chunk: row = ncol + fr, col = fk8
        const __bf16* bbase = Bt + (size_t)(ncol + fr) * 128 + fk8;

        f32x4 acc2[2][4] = {};
#pragma unroll
        for (int ks = 0; ks < 4; ++ks) {
#pragma unroll
            for (int nf = 0; nf < 4; ++nf) {
                bf16x8 bfv = *reinterpret_cast<const bf16x8*>(
                    bbase + (size_t)nf * 16 * 128 + ks * 32);
#pragma unroll
                for (int mf = 0; mf < 2; ++mf)
                    acc2[mf][nf] = __builtin_amdgcn_mfma_f32_16x16x32_bf16(
                        uf[mf][ks], bfv, acc2[mf][nf], 0, 0, 0);
            }
        }

        // store: 64B-contiguous segments per 16-lane group
#pragma unroll
        for (int mf = 0; mf < 2; ++mf) {
            const int orow = brow + mf * 16 + ((lane >> 4) << 2);
#pragma unroll
            for (int nf = 0; nf < 4; ++nf) {
                const int ocol = ncol + nf * 16 + fr;
#pragma unroll
                for (int v = 0; v < 4; ++v)
                    out[(size_t)(orow + v) * 4096 + ocol] = acc2[mf][nf][v];
            }
        }
    }
}

// ---------------------------------------------------------------------------
extern "C" void kernel_launch(void* const* d_in, const int* in_sizes, int n_in,
                              void* d_out, int out_size, void* d_ws, size_t ws_size,
                              hipStream_t stream) {
    const float* inp = (const float*)d_in[0];   // [8192,4096]
    const float* A   = (const float*)d_in[1];   // [4096,128]
    const float* B   = (const float*)d_in[2];   // [128,4096]
    float* out = (float*)d_out;                 // [8192,4096]

    char* ws = (char*)d_ws;
    __bf16* At = (__bf16*)(ws);                       // [128][4096]  1 MB
    __bf16* Bt = (__bf16*)(ws + (1 << 20));           // [4096][128]  1 MB

    // A[4096,128] -> At[128,4096];  B[128,4096] -> Bt[4096,128]
    tcast<<<dim3(128 / 32, 4096 / 32), 256, 0, stream>>>(A, At, 4096, 128);
    tcast<<<dim3(4096 / 32, 128 / 32), 256, 0, stream>>>(B, Bt, 128, 4096);

    fused_lora<<<256, 512, 0, stream>>>(inp, At, Bt, out);
}

// Round 4
// 74.443 us; speedup vs baseline: 2.1970x; 2.1970x over previous
//
#include <hip/hip_runtime.h>
#include <hip/hip_bf16.h>

typedef __bf16 bf16x8 __attribute__((ext_vector_type(8)));
typedef __bf16 bf16x4 __attribute__((ext_vector_type(4)));
typedef float  f32x4  __attribute__((ext_vector_type(4)));
typedef unsigned int u32x4 __attribute__((ext_vector_type(4)));

// ---------------------------------------------------------------------------
// Transpose + cast fp32 -> bf16:  dst[c][r] = (bf16)src[r][c]
// grid: (C/32, R/32), block 256 (32x8)
// ---------------------------------------------------------------------------
__global__ void tcast(const float* __restrict__ src, __bf16* __restrict__ dst,
                      int R, int C) {
    __shared__ float tile[32][33];
    const int bc = blockIdx.x * 32;   // col base in src
    const int br = blockIdx.y * 32;   // row base in src
    const int tx = threadIdx.x & 31;
    const int ty = threadIdx.x >> 5;  // 0..7
#pragma unroll
    for (int p = 0; p < 4; ++p)
        tile[ty + p * 8][tx] = src[(size_t)(br + ty + p * 8) * C + bc + tx];
    __syncthreads();
#pragma unroll
    for (int p = 0; p < 4; ++p)
        dst[(size_t)(bc + ty + p * 8) * R + br + tx] = (__bf16)tile[tx][ty + p * 8];
}

// ---------------------------------------------------------------------------
// GEMM1 (K-split): Up[ky][8192][128](bf16) = inp[:, ky-half](f32) @ A-half
// grid (256, KSPLIT) x 512 threads (8 waves: 2M x 4N). BM=32, BK=64.
// Double-buffered LDS, reg-staged fp32->bf16 convert. ktiles = 64/KSPLIT.
// 2 blocks/CU when KSPLIT=2 -> barrier drains overlap across blocks.
// ---------------------------------------------------------------------------
__global__ __launch_bounds__(512, 1) void gemm1b(const float* __restrict__ inp,
                                                 const __bf16* __restrict__ At,
                                                 __bf16* __restrict__ Uout,
                                                 int ktiles) {
    __shared__ __align__(16) __bf16 sI[2][32][64];    // 2 x 4 KB
    __shared__ __align__(16) __bf16 sA[2][128][64];   // 2 x 16 KB
    const int t     = threadIdx.x;
    const int brow  = blockIdx.x * 32;
    const int ktoff = blockIdx.y * ktiles;            // k-tile offset (x64 elems)
    __bf16* Up = Uout + (size_t)blockIdx.y * 8192 * 128;
    const int lane = t & 63;
    const int wid  = t >> 6;
    const int wm   = (wid >> 2) << 4;   // 0 / 16
    const int wn   = (wid & 3) << 5;    // 0 / 32 / 64 / 96

    // staging geometry
    const int irow = t >> 4;            // 0..31
    const int icol = (t & 15) << 2;     // 0..60, step 4
    // fragment geometry
    const int fr = lane & 15;
    const int fk = (lane >> 4) << 3;    // 0,8,16,24

    f32x4 acc[2] = {};
    f32x4 ireg;
    u32x4 areg[2];

    auto load_tile = [&](int kt) {
        const int kg = (ktoff + kt) * 64;
        ireg = *reinterpret_cast<const f32x4*>(
            &inp[(size_t)(brow + irow) * 4096 + kg + icol]);
#pragma unroll
        for (int p = 0; p < 2; ++p) {
            const int c = t + p * 512;
            const int row = c >> 3, col = (c & 7) << 3;
            areg[p] = *reinterpret_cast<const u32x4*>(
                &At[(size_t)row * 4096 + kg + col]);
        }
    };
    auto store_tile = [&](int buf) {
        bf16x4 h = { (__bf16)ireg[0], (__bf16)ireg[1], (__bf16)ireg[2], (__bf16)ireg[3] };
        *reinterpret_cast<bf16x4*>(&sI[buf][irow][icol ^ ((irow & 7) << 3)]) = h;
#pragma unroll
        for (int p = 0; p < 2; ++p) {
            const int c = t + p * 512;
            const int row = c >> 3, col = (c & 7) << 3;
            *reinterpret_cast<u32x4*>(&sA[buf][row][col ^ ((row & 7) << 3)]) = areg[p];
        }
    };

    load_tile(0);
    store_tile(0);
    int cur = 0;
    for (int kt = 0; kt < ktiles; ++kt) {
        if (kt < ktiles - 1) load_tile(kt + 1);   // overlap with compute below
        __syncthreads();                          // buf[cur] writes visible
#pragma unroll
        for (int ks = 0; ks < 2; ++ks) {
            const int k = ks * 32 + fk;
            const int ar = wm + fr;
            bf16x8 af = *reinterpret_cast<const bf16x8*>(
                &sI[cur][ar][k ^ ((ar & 7) << 3)]);
#pragma unroll
            for (int n = 0; n < 2; ++n) {
                const int nr = wn + n * 16 + fr;
                bf16x8 bfv = *reinterpret_cast<const bf16x8*>(
                    &sA[cur][nr][k ^ ((nr & 7) << 3)]);
                acc[n] = __builtin_amdgcn_mfma_f32_16x16x32_bf16(af, bfv, acc[n], 0, 0, 0);
            }
        }
        __syncthreads();                          // all reads of buf[cur] done
        if (kt < ktiles - 1) store_tile(cur ^ 1);
        cur ^= 1;
    }

    // epilogue: Up is bf16 [8192][128].  C/D: col=lane&15, row=(lane>>4)*4+v
    const int orow = brow + wm + ((lane >> 4) << 2);
#pragma unroll
    for (int n = 0; n < 2; ++n)
#pragma unroll
        for (int v = 0; v < 4; ++v)
            Up[(size_t)(orow + v) * 128 + wn + n * 16 + fr] = (__bf16)acc[n][v];
}

// ---------------------------------------------------------------------------
// Reduce the two K-split partials: U = bf16(Up[0] + Up[1]).  1M elems.
// 512 blocks x 256 thr x 8 bf16 each.
// ---------------------------------------------------------------------------
__global__ void reduceU(const __bf16* __restrict__ Up, __bf16* __restrict__ U) {
    const size_t i = ((size_t)blockIdx.x * 256 + threadIdx.x) * 8;
    bf16x8 a = *reinterpret_cast<const bf16x8*>(Up + i);
    bf16x8 b = *reinterpret_cast<const bf16x8*>(Up + (size_t)8192 * 128 + i);
    bf16x8 r;
#pragma unroll
    for (int j = 0; j < 8; ++j)
        r[j] = (__bf16)((float)a[j] + (float)b[j]);
    *reinterpret_cast<bf16x8*>(U + i) = r;
}

// ---------------------------------------------------------------------------
// GEMM2: out[8192][4096](f32) = U[8192][128](bf16) @ B  (B given as Bt[4096][128])
// K=128 staged entirely in LDS once. 4096 blocks x 256 thr (4 waves 2x2).
// BM=64, BN=128. 48KB LDS -> 3 blocks/CU resident pipeline.
// Bijective XCD swizzle (4096 = 8 x 512).
// ---------------------------------------------------------------------------
__global__ __launch_bounds__(256, 1) void gemm2(const __bf16* __restrict__ U,
                                                const __bf16* __restrict__ Bt,
                                                float* __restrict__ out) {
    __shared__ __align__(16) __bf16 sU[64][128];    // 16 KB
    __shared__ __align__(16) __bf16 sB[128][128];   // 32 KB
    const int t    = threadIdx.x;
    const int lane = t & 63;
    const int wid  = t >> 6;
    const int bx0  = blockIdx.x;
    const int bx   = (bx0 & 7) * 512 + (bx0 >> 3);  // XCD-contiguous chunks
    const int brow = (bx >> 5) * 64;    // 128 row tiles
    const int bcol = (bx & 31) * 128;   // 32 col tiles

    // stage U tile: 64 rows x 128 k
#pragma unroll
    for (int p = 0; p < 4; ++p) {
        const int c = t + p * 256;
        const int row = c >> 4, col = (c & 15) << 3;
        u32x4 v = *reinterpret_cast<const u32x4*>(&U[(size_t)(brow + row) * 128 + col]);
        *reinterpret_cast<u32x4*>(&sU[row][col ^ ((row & 7) << 3)]) = v;
    }
    // stage Bt tile: 128 n-rows x 128 k
#pragma unroll
    for (int p = 0; p < 8; ++p) {
        const int c = t + p * 256;
        const int row = c >> 4, col = (c & 15) << 3;
        u32x4 v = *reinterpret_cast<const u32x4*>(&Bt[(size_t)(bcol + row) * 128 + col]);
        *reinterpret_cast<u32x4*>(&sB[row][col ^ ((row & 7) << 3)]) = v;
    }
    __syncthreads();

    const int wm = (wid >> 1) << 5;   // 0 / 32
    const int wn = (wid & 1) << 6;    // 0 / 64
    const int fr = lane & 15;
    const int fk = (lane >> 4) << 3;

    f32x4 acc[2][4] = {};
#pragma unroll
    for (int ks = 0; ks < 4; ++ks) {
        const int k = ks * 32 + fk;
        bf16x8 af[2];
#pragma unroll
        for (int am = 0; am < 2; ++am) {
            const int r = wm + am * 16 + fr;
            af[am] = *reinterpret_cast<const bf16x8*>(&sU[r][k ^ ((r & 7) << 3)]);
        }
#pragma unroll
        for (int bn = 0; bn < 4; ++bn) {
            const int r = wn + bn * 16 + fr;
            bf16x8 bfv = *reinterpret_cast<const bf16x8*>(&sB[r][k ^ ((r & 7) << 3)]);
#pragma unroll
            for (int am = 0; am < 2; ++am)
                acc[am][bn] = __builtin_amdgcn_mfma_f32_16x16x32_bf16(af[am], bfv, acc[am][bn], 0, 0, 0);
        }
    }

    // epilogue: fp32 stores (16-lane groups hit contiguous 64B segments)
#pragma unroll
    for (int am = 0; am < 2; ++am) {
        const int orow = brow + wm + am * 16 + ((lane >> 4) << 2);
#pragma unroll
        for (int bn = 0; bn < 4; ++bn) {
            const int ocol = bcol + wn + bn * 16 + fr;
#pragma unroll
            for (int v = 0; v < 4; ++v)
                out[(size_t)(orow + v) * 4096 + ocol] = acc[am][bn][v];
        }
    }
}

// ---------------------------------------------------------------------------
extern "C" void kernel_launch(void* const* d_in, const int* in_sizes, int n_in,
                              void* d_out, int out_size, void* d_ws, size_t ws_size,
                              hipStream_t stream) {
    const float* inp = (const float*)d_in[0];   // [8192,4096]
    const float* A   = (const float*)d_in[1];   // [4096,128]
    const float* B   = (const float*)d_in[2];   // [128,4096]
    float* out = (float*)d_out;                 // [8192,4096]

    char* ws = (char*)d_ws;
    __bf16* At = (__bf16*)(ws);                       // [128][4096]   1 MB
    __bf16* Bt = (__bf16*)(ws + (1 << 20));           // [4096][128]   1 MB
    __bf16* U  = (__bf16*)(ws + (2 << 20));           // [8192][128]   2 MB
    __bf16* Up = (__bf16*)(ws + (4 << 20));           // [2][8192][128] 4 MB

    // A[4096,128] -> At[128,4096];  B[128,4096] -> Bt[4096,128]
    tcast<<<dim3(128 / 32, 4096 / 32), 256, 0, stream>>>(A, At, 4096, 128);
    tcast<<<dim3(4096 / 32, 128 / 32), 256, 0, stream>>>(B, Bt, 128, 4096);

    if (ws_size >= (size_t)(8 << 20)) {
        // K-split 2: 512 blocks (2/CU) -> barrier drains overlap across blocks
        gemm1b<<<dim3(256, 2), 512, 0, stream>>>(inp, At, Up, 32);
        reduceU<<<512, 256, 0, stream>>>(Up, U);
    } else {
        gemm1b<<<dim3(256, 1), 512, 0, stream>>>(inp, At, U, 64);
    }

    gemm2<<<4096, 256, 0, stream>>>(U, Bt, out);
}